// Round 13
// baseline (528.596 us; speedup 1.0000x reference)
//
#include <hip/hip_runtime.h>
#include <hip/hip_bf16.h>
#include <stdint.h>

// ---------------------------------------------------------------------------
// SelfAttention QKV projection + head-indexed RoPE, MI355X (gfx950)
//   q = rope(x @ Wq), k = rope(x @ Wk), v = x @ Wv   (pos = head index!)
// Round 13: B operand loaded GLOBAL->REGISTERS from a FRAGMENT-PACKED
//   layout (prep kernel packs W into MFMA-frag order: each wave's B-frag
//   load is base+lane*16 = one contiguous 1KB transaction). B never
//   touches LDS -> LDS traffic/tile 320->160 KB, below the MFMA floor.
//   XCD swizzle = column-panel per XCD so B slice (~1-2 MB) is L2-resident.
//   Sync: one counted-wait chain (compiler vmcnt(6)/(2)) + one manual
//   vmcnt(0)+barrier per tile for the A-DMA double buffer.
// ---------------------------------------------------------------------------

typedef __attribute__((ext_vector_type(8))) short short8;
typedef __attribute__((ext_vector_type(4))) float f32x4;

__device__ __forceinline__ unsigned short f2bf(float f) {
  __bf16 h = (__bf16)f;
  return __builtin_bit_cast(unsigned short, h);
}

__device__ __forceinline__ void gload_lds16(const void* g, void* l) {
  __builtin_amdgcn_global_load_lds((const __attribute__((address_space(1))) void*)g,
                                   (__attribute__((address_space(3))) void*)l,
                                   16, 0, 0);
}

// ---------------- prep kernels ----------------

__global__ __launch_bounds__(256) void convert_x(const float* __restrict__ X,
                                                 unsigned short* __restrict__ Xb,
                                                 int n8) {
  const int stride = gridDim.x * blockDim.x;
  for (int i = blockIdx.x * blockDim.x + threadIdx.x; i < n8; i += stride) {
    const float4 v0 = ((const float4*)X)[(size_t)i * 2 + 0];
    const float4 v1 = ((const float4*)X)[(size_t)i * 2 + 1];
    uint4 w;
    w.x = (uint32_t)f2bf(v0.x) | ((uint32_t)f2bf(v0.y) << 16);
    w.y = (uint32_t)f2bf(v0.z) | ((uint32_t)f2bf(v0.w) << 16);
    w.z = (uint32_t)f2bf(v1.x) | ((uint32_t)f2bf(v1.y) << 16);
    w.w = (uint32_t)f2bf(v1.z) | ((uint32_t)f2bf(v1.w) << 16);
    ((uint4*)Xb)[i] = w;
  }
}

// W (2048x2048 f32, K x N) -> Bpack: fragment-major bf16.
// Bpack elem index = ((nb*64 + kb)*64 + lane)*8 + j, where
//   nb = global col/16 (z*128 + within-z), kb = k/32, lane = lg*16+l15,
//   value = W[k = kb*32 + lg*8 + j][col = nb*16 + l15].
__global__ __launch_bounds__(256) void pack_cvt3(const float* __restrict__ W0,
                                                 const float* __restrict__ W1,
                                                 const float* __restrict__ W2,
                                                 unsigned short* __restrict__ Bpack) {
  __shared__ unsigned short tile[64][65];   // [k-row][n-col]
  const int z = blockIdx.z;
  const float* W = (z == 0) ? W0 : (z == 1) ? W1 : W2;
  const int bx = blockIdx.x * 64;           // N origin
  const int by = blockIdx.y * 64;           // K origin
  const int t  = threadIdx.x;
  const int tr = t >> 4;
  const int tc = (t & 15) * 4;
#pragma unroll
  for (int i = 0; i < 4; ++i) {
    const int r = tr + i * 16;
    const float4 v = *(const float4*)&W[(size_t)(by + r) * 2048 + bx + tc];
    tile[r][tc + 0] = f2bf(v.x);
    tile[r][tc + 1] = f2bf(v.y);
    tile[r][tc + 2] = f2bf(v.z);
    tile[r][tc + 3] = f2bf(v.w);
  }
  __syncthreads();
  const int f   = t >> 5;                   // 0..7: frag within tile
  const int nbi = f >> 1, kbi = f & 1;
  const int sub = t & 31;
#pragma unroll
  for (int li = 0; li < 2; ++li) {
    const int l = sub * 2 + li;             // lane 0..63
    const int c = nbi * 16 + (l & 15);
    short8 o;
#pragma unroll
    for (int j = 0; j < 8; ++j)
      o[j] = (short)tile[kbi * 32 + ((l >> 4) << 3) + j][c];
    const size_t nb = (size_t)z * 128 + blockIdx.x * 4 + nbi;
    const size_t kb = blockIdx.y * 2 + kbi;
    *(short8*)&Bpack[((nb * 64 + kb) * 64 + l) * 8] = o;
  }
}

// ---------------- fused 256x256 GEMM, BK=64, B-from-global (packed) --------
// LDS (64 KB): A dbuf, buf b at b*32KB, A[256][64] bf16, 128B rows,
//   swizzle: 16B slot s_phys = s_log ^ (row&7); frag byte = s0 ^ (ks<<6).
// Per tile t: [b0 x4 plain loads][b1 x4][GLD_A(t+1) x2]; a-reads + MFMA;
//   compiler waits vmcnt(6) at c0, vmcnt(2) at c1 (in-order queue);
//   manual vmcnt(0)+barrier at tile end drains A(t+1) (issued ~2000 cyc
//   earlier -> free). WAR: buf (t+1)&1's readers finished in tile t-1,
//   before barrier(t-1) < GLD_A(t+1) issue. RAW: A(t) drained by the
//   end-of-(t-1) vmcnt(0).

__global__ __launch_bounds__(1024, 4) void qkv_fused18(const unsigned short* __restrict__ Xb,
                                                       const unsigned short* __restrict__ Bpack,
                                                       float* __restrict__ Out) {
  extern __shared__ char smem[];            // 64 KB: A double buffer

  // column-panel-per-XCD swizzle: 1536 blocks = 64 mb x 24 nb, 8 XCDs
  const int wg  = blockIdx.x;
  const int xcd = wg & 7;
  const int idx = wg >> 3;                  // 0..191
  const int nb  = xcd * 3 + (idx >> 6);     // 0..23
  const int mb  = idx & 63;                 // 0..63
  const int m0  = mb * 256, n0 = nb * 256;

  const int tid  = threadIdx.x;
  const int wave = tid >> 6, lane = tid & 63;
  const int l15  = lane & 15, lg = lane >> 4;
  const int wm   = (wave >> 2) * 64;        // 4 wave-rows
  const int wn   = (wave & 3) * 64;         // 4 wave-cols
  const int s0   = ((lg ^ (l15 & 7)) << 4); // ks0 frag slot; ks1 = s0^64

  const unsigned short* Xp = Xb + (size_t)m0 * 2048;
  // per-lane packed-B base: nb16 block (n0+wn)/16, lane offset
  const unsigned short* Bp = Bpack + (size_t)((n0 + wn) >> 4) * 32768 + lane * 8;

  const int srow  = tid >> 3;               // 0..127
  const int sslot = tid & 7;                // physical 16B slot

  f32x4 acc[4][4] = {};

#define GLD_A(TP1)                                                            \
  do {                                                                        \
    char* dst_ = smem + (((TP1) & 1) << 15);                                  \
    _Pragma("unroll") for (int i_ = 0; i_ < 2; ++i_) {                        \
      const int row_ = i_ * 128 + srow;                                       \
      gload_lds16(Xp + (size_t)row_ * 2048 + (TP1) * 64 +                     \
                      ((sslot ^ (row_ & 7)) << 3),                            \
                  dst_ + i_ * 16384 + tid * 16);                              \
    }                                                                         \
  } while (0)

#define LDB4G(DST, T, KS)                                                     \
  _Pragma("unroll") for (int ni_ = 0; ni_ < 4; ++ni_)                         \
      (DST)[ni_] = *(const short8*)(Bp + ni_ * 32768 +                        \
                                    (2 * (T) + (KS)) * 512);

#define LDA4(DST, KS)                                                         \
  _Pragma("unroll") for (int mi_ = 0; mi_ < 4; ++mi_)                         \
      (DST)[mi_] = *(const short8*)(Ab +                                      \
          ((wm + mi_ * 16 + l15) << 7) + (s0 ^ ((KS) << 6)));

#define MFMA16(AR, BR)                                                        \
  do {                                                                        \
    __builtin_amdgcn_s_setprio(1);                                            \
    _Pragma("unroll") for (int mi_ = 0; mi_ < 4; ++mi_)                       \
      _Pragma("unroll") for (int ni_ = 0; ni_ < 4; ++ni_)                     \
        asm("v_mfma_f32_16x16x32_bf16 %0, %1, %2, %0"                         \
            : "+v"(acc[mi_][ni_])                                             \
            : "v"((AR)[mi_]), "v"((BR)[ni_]));                                \
    __builtin_amdgcn_s_setprio(0);                                            \
  } while (0)

  // prologue: stage A(0), drain, sync
  GLD_A(0);
  asm volatile("s_waitcnt vmcnt(0)" ::: "memory");
  __builtin_amdgcn_s_barrier();

  for (int t = 0; t < 32; ++t) {
    const char* Ab = smem + ((t & 1) << 15);
    short8 b0[4], b1[4], a[4];

    LDB4G(b0, t, 0);                  // plain loads, compiler-counted waits
    LDB4G(b1, t, 1);
    if (t < 31) GLD_A(t + 1);         // issued last -> stays in flight
    LDA4(a, 0);
    MFMA16(a, b0);                    // c0: waits vmcnt(6) + lgkm(a)
    LDA4(a, 1);
    MFMA16(a, b1);                    // c1: waits vmcnt(2)
    asm volatile("s_waitcnt vmcnt(0)" ::: "memory");  // drain A(t+1), ~free
    if (t < 31) __builtin_amdgcn_s_barrier();
  }

#undef GLD_A
#undef LDB4G
#undef LDA4
#undef MFMA16

  // epilogue: fused RoPE. C layout: col=lane&15, row=(lane>>4)*4+reg.
#pragma unroll
  for (int ni = 0; ni < 4; ++ni) {
    const int col = n0 + wn + ni * 16 + l15;
    const int sec = col >> 11;                 // 0=q,1=k,2=v
    const int lc  = col & 2047;
    float c = 1.0f, ssg = 0.0f;
    if (sec < 2) {
      const int h = lc >> 7;
      const int p = (lc & 127) >> 1;
      const float theta = exp2f(-(float)p * 0.20762050593046014f); // log2(1e4)/64
      float s;
      sincosf((float)h * theta, &s, &c);
      ssg = (l15 & 1) ? s : -s;
    }
    float* outp = Out + (size_t)sec * 33554432 + lc;
#pragma unroll
    for (int mi = 0; mi < 4; ++mi) {
      const f32x4 a = acc[mi][ni];
#pragma unroll
      for (int r = 0; r < 4; ++r) {
        const float val = a[r];
        float res = val;
        if (sec < 2) {
          const float other = __shfl_xor(val, 1);
          res = val * c + other * ssg;
        }
        __builtin_nontemporal_store(
            res, outp + (size_t)(m0 + wm + mi * 16 + lg * 4 + r) * 2048);
      }
    }
  }
}

extern "C" void kernel_launch(void* const* d_in, const int* in_sizes, int n_in,
                              void* d_out, int out_size, void* d_ws, size_t ws_size,
                              hipStream_t stream) {
  (void)in_sizes; (void)n_in; (void)out_size;
  const float* x  = (const float*)d_in[0];
  const float* Wq = (const float*)d_in[1];
  const float* Wk = (const float*)d_in[2];
  const float* Wv = (const float*)d_in[3];
  float* out = (float*)d_out;

  const size_t XB_ELEMS = 16384ull * 2048;
  const size_t BP_ELEMS = 6144ull * 2048;

  unsigned short* Xb = (unsigned short*)d_ws;
  unsigned short* Bp = Xb + XB_ELEMS;
  (void)ws_size;  // 88 MiB required; same budget as rounds 2-12 (verified fit)

  convert_x<<<2048, 256, 0, stream>>>(x, Xb, (int)(XB_ELEMS / 8));
  pack_cvt3<<<dim3(32, 32, 3), 256, 0, stream>>>(Wq, Wk, Wv, Bp);
  hipFuncSetAttribute((const void*)qkv_fused18,
                      hipFuncAttributeMaxDynamicSharedMemorySize, 65536);
  qkv_fused18<<<1536, 1024, 65536, stream>>>(Xb, Bp, out);
  (void)BP_ELEMS;
}

// Round 16
// 412.269 us; speedup vs baseline: 1.2822x; 1.2822x over previous
//
#include <hip/hip_runtime.h>
#include <hip/hip_bf16.h>
#include <stdint.h>

// ---------------------------------------------------------------------------
// SelfAttention QKV projection + head-indexed RoPE, MI355X (gfx950)
//   q = rope(x @ Wq), k = rope(x @ Wk), v = x @ Wv   (pos = head index!)
// Round 16: LOCK IN round-12 (session Pareto best, verified passing).
//   r13-r15's packed-B branch abandoned: cross-tile register time-share of
//   plain loads around raw s_barrier is not provably orderable at HIP level
//   (rule #18 class); two correctness failures. This kernel: 256x256 tile,
//   BK=64, 16 waves @4/SIMD, A dbuf DMA + B tri-buffer (160 KB LDS),
//   0-conflict XOR swizzle, counted vmcnt(2) gate, 1 barrier/tile,
//   XCD swizzle, setprio, fused RoPE, nontemporal stores.
// ---------------------------------------------------------------------------

typedef __attribute__((ext_vector_type(8))) short short8;
typedef __attribute__((ext_vector_type(4))) float f32x4;

__device__ __forceinline__ unsigned short f2bf(float f) {
  __bf16 h = (__bf16)f;
  return __builtin_bit_cast(unsigned short, h);
}

__device__ __forceinline__ void gload_lds16(const void* g, void* l) {
  __builtin_amdgcn_global_load_lds((const __attribute__((address_space(1))) void*)g,
                                   (__attribute__((address_space(3))) void*)l,
                                   16, 0, 0);
}

// ---------------- prep kernels ----------------

__global__ __launch_bounds__(256) void convert_x(const float* __restrict__ X,
                                                 unsigned short* __restrict__ Xb,
                                                 int n8) {
  const int stride = gridDim.x * blockDim.x;
  for (int i = blockIdx.x * blockDim.x + threadIdx.x; i < n8; i += stride) {
    const float4 v0 = ((const float4*)X)[(size_t)i * 2 + 0];
    const float4 v1 = ((const float4*)X)[(size_t)i * 2 + 1];
    uint4 w;
    w.x = (uint32_t)f2bf(v0.x) | ((uint32_t)f2bf(v0.y) << 16);
    w.y = (uint32_t)f2bf(v0.z) | ((uint32_t)f2bf(v0.w) << 16);
    w.z = (uint32_t)f2bf(v1.x) | ((uint32_t)f2bf(v1.y) << 16);
    w.w = (uint32_t)f2bf(v1.z) | ((uint32_t)f2bf(v1.w) << 16);
    ((uint4*)Xb)[i] = w;
  }
}

// W (2048x2048 f32, K x N) -> WT (bf16, N x K); z selects which W.
__global__ __launch_bounds__(256) void transpose_cvt3(const float* __restrict__ W0,
                                                      const float* __restrict__ W1,
                                                      const float* __restrict__ W2,
                                                      unsigned short* __restrict__ WT) {
  __shared__ unsigned short tile[64][65];
  const int z = blockIdx.z;
  const float* W = (z == 0) ? W0 : (z == 1) ? W1 : W2;
  unsigned short* WTz = WT + (size_t)z * 2048 * 2048;
  const int bx = blockIdx.x * 64;             // N origin
  const int by = blockIdx.y * 64;             // K origin
  const int t  = threadIdx.x;
  const int tr = t >> 4;
  const int tc = (t & 15) * 4;
#pragma unroll
  for (int i = 0; i < 4; ++i) {
    const int r = tr + i * 16;
    const float4 v = *(const float4*)&W[(size_t)(by + r) * 2048 + bx + tc];
    tile[r][tc + 0] = f2bf(v.x);
    tile[r][tc + 1] = f2bf(v.y);
    tile[r][tc + 2] = f2bf(v.z);
    tile[r][tc + 3] = f2bf(v.w);
  }
  __syncthreads();
#pragma unroll
  for (int i = 0; i < 4; ++i) {
    const int a = tr + i * 16;
    ushort4 o;
    o.x = tile[tc + 0][a];
    o.y = tile[tc + 1][a];
    o.z = tile[tc + 2][a];
    o.w = tile[tc + 3][a];
    *(ushort4*)&WTz[(size_t)(bx + a) * 2048 + by + tc] = o;
  }
}

// ---------------- fused 256x256 GEMM, BK=64, 16 waves, B tri-buffer --------
// LDS (160 KB): A bufs at 0, 32768 (t&1); B bufs at 65536 + (t%3)*32768.
// Swizzle: 16B slot s_phys = s_log ^ (row&7); frag byte = s0 ^ (kk<<6).
// Tile body: GLD_A(t+1); read b0,a0; MFMA c0; GLD_B(t+2)->buf (t+2)%3;
//   read b1,a1; MFMA c1; gate vmcnt(2); barrier.   (NO mid-tile sync)
// WAR: writer of B buf t%3 is B(t+3), issued after barrier t; all reads of
//   it complete before barrier t (MFMA operand dependency). A(t+1) targets
//   buf read in t-1, finished before barrier t-1.
// RAW: gate queue = B(t+1)x2, A(t+1)x2, B(t+2)x2 -> vmcnt(2) drains
//   A(t+1)+B(t+1), keeps B(t+2). Prologue A(0),B(0),B(1)+vmcnt(2) matches.
//   t=30 gate vmcnt(0); t=31 no stage/gate.

__global__ __launch_bounds__(1024, 4) void qkv_fused17(const unsigned short* __restrict__ Xb,
                                                       const unsigned short* __restrict__ WT,
                                                       float* __restrict__ Out) {
  extern __shared__ char smem[];

  // XCD-aware swizzle (1536 blocks, 1536 % 8 == 0 -> bijective)
  const int wg  = blockIdx.x;
  const int swz = (wg & 7) * 192 + (wg >> 3);
  const int mb  = swz / 24, nb = swz % 24;
  const int m0  = mb * 256, n0 = nb * 256;

  const int tid  = threadIdx.x;
  const int wave = tid >> 6, lane = tid & 63;
  const int l15  = lane & 15, lg = lane >> 4;
  const int wm   = (wave >> 2) * 64;           // 4 wave-rows
  const int wn   = (wave & 3) * 64;            // 4 wave-cols
  const int s0   = ((lg ^ (l15 & 7)) << 4);    // kk0 frag slot; kk1 = s0^64

  const unsigned short* Xp = Xb + (size_t)m0 * 2048;
  const unsigned short* Wp = WT + (size_t)n0 * 2048;

  const int srow  = tid >> 3;                  // 0..127
  const int sslot = tid & 7;                   // physical 16B slot

  f32x4 acc[4][4] = {};

#define GLD_A(TP1)                                                            \
  do {                                                                        \
    char* dst_ = smem + (((TP1) & 1) << 15);                                  \
    _Pragma("unroll") for (int i_ = 0; i_ < 2; ++i_) {                        \
      const int row_ = i_ * 128 + srow;                                       \
      gload_lds16(Xp + (size_t)row_ * 2048 + (TP1) * 64 +                     \
                      ((sslot ^ (row_ & 7)) << 3),                            \
                  dst_ + i_ * 16384 + tid * 16);                              \
    }                                                                         \
  } while (0)

#define GLD_B(TP2, BUFI)                                                      \
  do {                                                                        \
    char* dst_ = smem + 65536 + (BUFI) * 32768;                               \
    _Pragma("unroll") for (int i_ = 0; i_ < 2; ++i_) {                        \
      const int row_ = i_ * 128 + srow;                                       \
      gload_lds16(Wp + (size_t)row_ * 2048 + (TP2) * 64 +                     \
                      ((sslot ^ (row_ & 7)) << 3),                            \
                  dst_ + i_ * 16384 + tid * 16);                              \
    }                                                                         \
  } while (0)

#define LDA4(DST, KS)                                                         \
  _Pragma("unroll") for (int mi_ = 0; mi_ < 4; ++mi_)                         \
      (DST)[mi_] = *(const short8*)(Ab +                                      \
          ((wm + mi_ * 16 + l15) << 7) + (s0 ^ ((KS) << 6)));

#define LDB4(DST, KS)                                                         \
  _Pragma("unroll") for (int ni_ = 0; ni_ < 4; ++ni_)                         \
      (DST)[ni_] = *(const short8*)(Bb +                                      \
          ((wn + ni_ * 16 + l15) << 7) + (s0 ^ ((KS) << 6)));

#define MFMA16(AR, BR)                                                        \
  do {                                                                        \
    __builtin_amdgcn_s_setprio(1);                                            \
    _Pragma("unroll") for (int mi_ = 0; mi_ < 4; ++mi_)                       \
      _Pragma("unroll") for (int ni_ = 0; ni_ < 4; ++ni_)                     \
        asm("v_mfma_f32_16x16x32_bf16 %0, %1, %2, %0"                         \
            : "+v"(acc[mi_][ni_])                                             \
            : "v"((AR)[mi_]), "v"((BR)[ni_]));                                \
    __builtin_amdgcn_s_setprio(0);                                            \
  } while (0)

  // prologue: A(0)->buf0, B(0)->buf0, B(1)->buf1; gate leaves B(1) in flight
  GLD_A(0);
  GLD_B(0, 0);
  GLD_B(1, 1);
  asm volatile("s_waitcnt vmcnt(2)" ::: "memory");
  __builtin_amdgcn_s_barrier();

  int bc = 0;                                  // B buffer index for tile t
  for (int t = 0; t < 32; ++t) {
    const char* Ab = smem + ((t & 1) << 15);
    const char* Bb = smem + 65536 + bc * 32768;
    const int bn2 = (bc == 0) ? 2 : bc - 1;    // (bc+2)%3
    short8 a0[4], b0[4], a1[4], b1[4];

    if (t < 31) GLD_A(t + 1);
    LDB4(b0, 0);
    LDA4(a0, 0);
    MFMA16(a0, b0);                    // c0 — compiler-counted lgkm waits
    if (t < 30) GLD_B(t + 2, bn2);     // never a buffer being read
    LDB4(b1, 1);
    LDA4(a1, 1);
    MFMA16(a1, b1);                    // c1
    if (t == 30)     asm volatile("s_waitcnt vmcnt(0)" ::: "memory");
    else if (t < 30) asm volatile("s_waitcnt vmcnt(2)" ::: "memory");
    if (t < 31) __builtin_amdgcn_s_barrier();
    bc = (bc == 2) ? 0 : bc + 1;
  }

#undef GLD_A
#undef GLD_B
#undef LDA4
#undef LDB4
#undef MFMA16

  // epilogue: fused RoPE. C layout: col=lane&15, row=(lane>>4)*4+reg.
#pragma unroll
  for (int ni = 0; ni < 4; ++ni) {
    const int col = n0 + wn + ni * 16 + l15;
    const int sec = col >> 11;                 // 0=q,1=k,2=v
    const int lc  = col & 2047;
    float c = 1.0f, ssg = 0.0f;
    if (sec < 2) {
      const int h = lc >> 7;
      const int p = (lc & 127) >> 1;
      const float theta = exp2f(-(float)p * 0.20762050593046014f); // log2(1e4)/64
      float s;
      sincosf((float)h * theta, &s, &c);
      ssg = (l15 & 1) ? s : -s;
    }
    float* outp = Out + (size_t)sec * 33554432 + lc;
#pragma unroll
    for (int mi = 0; mi < 4; ++mi) {
      const f32x4 a = acc[mi][ni];
#pragma unroll
      for (int r = 0; r < 4; ++r) {
        const float val = a[r];
        float res = val;
        if (sec < 2) {
          const float other = __shfl_xor(val, 1);
          res = val * c + other * ssg;
        }
        __builtin_nontemporal_store(
            res, outp + (size_t)(m0 + wm + mi * 16 + lg * 4 + r) * 2048);
      }
    }
  }
}

// ---------------- r11 kernel kept as fallback (128 KB LDS) ----------------
__global__ __launch_bounds__(1024, 4) void qkv_fused16(const unsigned short* __restrict__ Xb,
                                                       const unsigned short* __restrict__ WT,
                                                       float* __restrict__ Out) {
  extern __shared__ char smem[];
  const int wg  = blockIdx.x;
  const int swz = (wg & 7) * 192 + (wg >> 3);
  const int mb  = swz / 24, nb = swz % 24;
  const int m0  = mb * 256, n0 = nb * 256;

  const int tid  = threadIdx.x;
  const int wave = tid >> 6, lane = tid & 63;
  const int l15  = lane & 15, lg = lane >> 4;
  const int wm   = (wave >> 2) * 64;
  const int wn   = (wave & 3) * 64;
  const int s0   = ((lg ^ (l15 & 7)) << 4);

  const unsigned short* Xp = Xb + (size_t)m0 * 2048;
  const unsigned short* Wp = WT + (size_t)n0 * 2048;

  const int srow  = tid >> 3;
  const int sslot = tid & 7;

  f32x4 acc[4][4] = {};

#define GLD_A(TP1)                                                            \
  do {                                                                        \
    char* dst_ = smem + (((TP1) & 1) << 16);                                  \
    _Pragma("unroll") for (int i_ = 0; i_ < 2; ++i_) {                        \
      const int row_ = i_ * 128 + srow;                                       \
      gload_lds16(Xp + (size_t)row_ * 2048 + (TP1) * 64 +                     \
                      ((sslot ^ (row_ & 7)) << 3),                            \
                  dst_ + i_ * 16384 + tid * 16);                              \
    }                                                                         \
  } while (0)

#define GLD_B(TP2)                                                            \
  do {                                                                        \
    char* dst_ = smem + (((TP2) & 1) << 16) + 32768;                          \
    _Pragma("unroll") for (int i_ = 0; i_ < 2; ++i_) {                        \
      const int row_ = i_ * 128 + srow;                                       \
      gload_lds16(Wp + (size_t)row_ * 2048 + (TP2) * 64 +                     \
                      ((sslot ^ (row_ & 7)) << 3),                            \
                  dst_ + i_ * 16384 + tid * 16);                              \
    }                                                                         \
  } while (0)

#define LDA4(DST, KS)                                                         \
  _Pragma("unroll") for (int mi_ = 0; mi_ < 4; ++mi_)                         \
      (DST)[mi_] = *(const short8*)(Ab +                                      \
          ((wm + mi_ * 16 + l15) << 7) + (s0 ^ ((KS) << 6)));

#define LDB4(DST, KS)                                                         \
  _Pragma("unroll") for (int ni_ = 0; ni_ < 4; ++ni_)                         \
      (DST)[ni_] = *(const short8*)(Bb +                                      \
          ((wn + ni_ * 16 + l15) << 7) + (s0 ^ ((KS) << 6)));

#define MFMA16(AR, BR)                                                        \
  do {                                                                        \
    __builtin_amdgcn_s_setprio(1);                                            \
    _Pragma("unroll") for (int mi_ = 0; mi_ < 4; ++mi_)                       \
      _Pragma("unroll") for (int ni_ = 0; ni_ < 4; ++ni_)                     \
        asm("v_mfma_f32_16x16x32_bf16 %0, %1, %2, %0"                         \
            : "+v"(acc[mi_][ni_])                                             \
            : "v"((AR)[mi_]), "v"((BR)[ni_]));                                \
    __builtin_amdgcn_s_setprio(0);                                            \
  } while (0)

  GLD_A(0);
  GLD_B(0);
  GLD_B(1);
  asm volatile("s_waitcnt vmcnt(2)" ::: "memory");
  __builtin_amdgcn_s_barrier();

  for (int t = 0; t < 32; ++t) {
    const char* Ab = smem + ((t & 1) << 16);
    const char* Bb = Ab + 32768;
    short8 a0[4], b0[4], a1[4], b1[4];

    if (t < 31) GLD_A(t + 1);
    LDB4(b0, 0);
    LDA4(a0, 0);
    MFMA16(a0, b0);
    LDB4(b1, 1);
    LDA4(a1, 1);
    asm volatile("s_waitcnt lgkmcnt(0)" ::: "memory");
    __builtin_amdgcn_s_barrier();
    if (t < 30) GLD_B(t + 2);
    MFMA16(a1, b1);
    if (t == 30)     asm volatile("s_waitcnt vmcnt(0)" ::: "memory");
    else if (t < 30) asm volatile("s_waitcnt vmcnt(2)" ::: "memory");
    if (t < 31) __builtin_amdgcn_s_barrier();
  }

#undef GLD_A
#undef GLD_B
#undef LDA4
#undef LDB4
#undef MFMA16

#pragma unroll
  for (int ni = 0; ni < 4; ++ni) {
    const int col = n0 + wn + ni * 16 + l15;
    const int sec = col >> 11;
    const int lc  = col & 2047;
    float c = 1.0f, ssg = 0.0f;
    if (sec < 2) {
      const int h = lc >> 7;
      const int p = (lc & 127) >> 1;
      const float theta = exp2f(-(float)p * 0.20762050593046014f);
      float s;
      sincosf((float)h * theta, &s, &c);
      ssg = (l15 & 1) ? s : -s;
    }
    float* outp = Out + (size_t)sec * 33554432 + lc;
#pragma unroll
    for (int mi = 0; mi < 4; ++mi) {
      const f32x4 a = acc[mi][ni];
#pragma unroll
      for (int r = 0; r < 4; ++r) {
        const float val = a[r];
        float res = val;
        if (sec < 2) {
          const float other = __shfl_xor(val, 1);
          res = val * c + other * ssg;
        }
        __builtin_nontemporal_store(
            res, outp + (size_t)(m0 + wm + mi * 16 + lg * 4 + r) * 2048);
      }
    }
  }
}

extern "C" void kernel_launch(void* const* d_in, const int* in_sizes, int n_in,
                              void* d_out, int out_size, void* d_ws, size_t ws_size,
                              hipStream_t stream) {
  (void)in_sizes; (void)n_in; (void)out_size;
  const float* x  = (const float*)d_in[0];
  const float* Wq = (const float*)d_in[1];
  const float* Wk = (const float*)d_in[2];
  const float* Wv = (const float*)d_in[3];
  float* out = (float*)d_out;

  const size_t XB_ELEMS = 16384ull * 2048;
  const size_t WT_ELEMS = 6144ull * 2048;

  if (ws_size >= (XB_ELEMS + WT_ELEMS) * sizeof(unsigned short)) {
    unsigned short* Xb  = (unsigned short*)d_ws;
    unsigned short* WTf = Xb + XB_ELEMS;
    convert_x<<<2048, 256, 0, stream>>>(x, Xb, (int)(XB_ELEMS / 8));
    transpose_cvt3<<<dim3(32, 32, 3), 256, 0, stream>>>(Wq, Wk, Wv, WTf);
    hipError_t e = hipFuncSetAttribute(
        (const void*)qkv_fused17,
        hipFuncAttributeMaxDynamicSharedMemorySize, 163840);
    if (e == hipSuccess) {
      qkv_fused17<<<1536, 1024, 163840, stream>>>(Xb, WTf, out);
    } else {
      hipFuncSetAttribute((const void*)qkv_fused16,
                          hipFuncAttributeMaxDynamicSharedMemorySize, 131072);
      qkv_fused16<<<1536, 1024, 131072, stream>>>(Xb, WTf, out);
    }
  } else {
    // minimal fallback: should not happen for this problem size
    unsigned short* Xb = (unsigned short*)d_ws;
    convert_x<<<2048, 256, 0, stream>>>(x, Xb, (int)(XB_ELEMS / 8));
  }
}

// Round 17
// 408.042 us; speedup vs baseline: 1.2954x; 1.0104x over previous
//
#include <hip/hip_runtime.h>
#include <hip/hip_bf16.h>
#include <stdint.h>

// ---------------------------------------------------------------------------
// SelfAttention QKV projection + head-indexed RoPE, MI355X (gfx950)
//   q = rope(x @ Wq), k = rope(x @ Wk), v = x @ Wv   (pos = head index!)
// Round 17: r16 (verified best) + low-risk bundle:
//   (1) setprio removed (m190: negative on non-8-phase GEMM),
//   (2) GLD_B(t+2) issued at tile top (same vmcnt(2) ledger, +800cyc flight),
//   (3) prep merged into ONE launch (z=0..2 transpose W, z=3 convert x).
//   Core unchanged: 256x256 tile, BK=64, 16 waves @4/SIMD, A dbuf DMA +
//   B tri-buffer (160 KB LDS), 0-conflict XOR swizzle, counted vmcnt(2)
//   gate, 1 barrier/tile, XCD swizzle, fused RoPE, nontemporal stores.
// ---------------------------------------------------------------------------

typedef __attribute__((ext_vector_type(8))) short short8;
typedef __attribute__((ext_vector_type(4))) float f32x4;

__device__ __forceinline__ unsigned short f2bf(float f) {
  __bf16 h = (__bf16)f;
  return __builtin_bit_cast(unsigned short, h);
}

__device__ __forceinline__ void gload_lds16(const void* g, void* l) {
  __builtin_amdgcn_global_load_lds((const __attribute__((address_space(1))) void*)g,
                                   (__attribute__((address_space(3))) void*)l,
                                   16, 0, 0);
}

// ---------------- merged prep kernel ----------------
// z = 0..2: transpose+convert Wz (2048x2048 f32 KxN) -> WT bf16 (NxK).
// z = 3: grid-stride convert x f32 -> bf16 (1024 blocks cover 16M elems).
__global__ __launch_bounds__(256) void prep_all(const float* __restrict__ X,
                                                const float* __restrict__ W0,
                                                const float* __restrict__ W1,
                                                const float* __restrict__ W2,
                                                unsigned short* __restrict__ Xb,
                                                unsigned short* __restrict__ WT) {
  const int z = blockIdx.z;
  if (z == 3) {
    // convert x: 32M elems / 8 per thread = 4M threads; grid-stride
    const int n8 = 16384 * 2048 / 8;
    const int nthreads = gridDim.x * gridDim.y * blockDim.x;
    int base = (blockIdx.y * gridDim.x + blockIdx.x) * blockDim.x + threadIdx.x;
    for (int i = base; i < n8; i += nthreads) {
      const float4 v0 = ((const float4*)X)[(size_t)i * 2 + 0];
      const float4 v1 = ((const float4*)X)[(size_t)i * 2 + 1];
      uint4 w;
      w.x = (uint32_t)f2bf(v0.x) | ((uint32_t)f2bf(v0.y) << 16);
      w.y = (uint32_t)f2bf(v0.z) | ((uint32_t)f2bf(v0.w) << 16);
      w.z = (uint32_t)f2bf(v1.x) | ((uint32_t)f2bf(v1.y) << 16);
      w.w = (uint32_t)f2bf(v1.z) | ((uint32_t)f2bf(v1.w) << 16);
      ((uint4*)Xb)[i] = w;
    }
    return;
  }
  __shared__ unsigned short tile[64][65];
  const float* W = (z == 0) ? W0 : (z == 1) ? W1 : W2;
  unsigned short* WTz = WT + (size_t)z * 2048 * 2048;
  const int bx = blockIdx.x * 64;             // N origin
  const int by = blockIdx.y * 64;             // K origin
  const int t  = threadIdx.x;
  const int tr = t >> 4;
  const int tc = (t & 15) * 4;
#pragma unroll
  for (int i = 0; i < 4; ++i) {
    const int r = tr + i * 16;
    const float4 v = *(const float4*)&W[(size_t)(by + r) * 2048 + bx + tc];
    tile[r][tc + 0] = f2bf(v.x);
    tile[r][tc + 1] = f2bf(v.y);
    tile[r][tc + 2] = f2bf(v.z);
    tile[r][tc + 3] = f2bf(v.w);
  }
  __syncthreads();
#pragma unroll
  for (int i = 0; i < 4; ++i) {
    const int a = tr + i * 16;
    ushort4 o;
    o.x = tile[tc + 0][a];
    o.y = tile[tc + 1][a];
    o.z = tile[tc + 2][a];
    o.w = tile[tc + 3][a];
    *(ushort4*)&WTz[(size_t)(bx + a) * 2048 + by + tc] = o;
  }
}

// ---------------- fused 256x256 GEMM, BK=64, 16 waves, B tri-buffer --------
// LDS (160 KB): A bufs at 0, 32768 (t&1); B bufs at 65536 + (t%3)*32768.
// Swizzle: 16B slot s_phys = s_log ^ (row&7); frag byte = s0 ^ (kk<<6).
// Tile body: GLD_A(t+1) + GLD_B(t+2) at TOP; read b0,a0; MFMA c0;
//   read b1,a1; MFMA c1; gate vmcnt(2); barrier.
// WAR: B(t+2) writes buf (t+2)%3, last read at tile t-1 (complete before
//   barrier t-1 < issue). A(t+1) targets buf read in t-1, same argument.
// RAW: gate queue = B(t+1)x2, A(t+1)x2, B(t+2)x2 -> vmcnt(2) drains
//   A(t+1)+B(t+1), keeps B(t+2). Prologue A(0),B(0),B(1)+vmcnt(2) matches.
//   t=30 gate vmcnt(0); t=31 no stage/gate.

__global__ __launch_bounds__(1024, 4) void qkv_fused21(const unsigned short* __restrict__ Xb,
                                                       const unsigned short* __restrict__ WT,
                                                       float* __restrict__ Out) {
  extern __shared__ char smem[];

  // XCD-aware swizzle (1536 blocks, 1536 % 8 == 0 -> bijective)
  const int wg  = blockIdx.x;
  const int swz = (wg & 7) * 192 + (wg >> 3);
  const int mb  = swz / 24, nb = swz % 24;
  const int m0  = mb * 256, n0 = nb * 256;

  const int tid  = threadIdx.x;
  const int wave = tid >> 6, lane = tid & 63;
  const int l15  = lane & 15, lg = lane >> 4;
  const int wm   = (wave >> 2) * 64;           // 4 wave-rows
  const int wn   = (wave & 3) * 64;            // 4 wave-cols
  const int s0   = ((lg ^ (l15 & 7)) << 4);    // kk0 frag slot; kk1 = s0^64

  const unsigned short* Xp = Xb + (size_t)m0 * 2048;
  const unsigned short* Wp = WT + (size_t)n0 * 2048;

  const int srow  = tid >> 3;                  // 0..127
  const int sslot = tid & 7;                   // physical 16B slot

  f32x4 acc[4][4] = {};

#define GLD_A(TP1)                                                            \
  do {                                                                        \
    char* dst_ = smem + (((TP1) & 1) << 15);                                  \
    _Pragma("unroll") for (int i_ = 0; i_ < 2; ++i_) {                        \
      const int row_ = i_ * 128 + srow;                                       \
      gload_lds16(Xp + (size_t)row_ * 2048 + (TP1) * 64 +                     \
                      ((sslot ^ (row_ & 7)) << 3),                            \
                  dst_ + i_ * 16384 + tid * 16);                              \
    }                                                                         \
  } while (0)

#define GLD_B(TP2, BUFI)                                                      \
  do {                                                                        \
    char* dst_ = smem + 65536 + (BUFI) * 32768;                               \
    _Pragma("unroll") for (int i_ = 0; i_ < 2; ++i_) {                        \
      const int row_ = i_ * 128 + srow;                                       \
      gload_lds16(Wp + (size_t)row_ * 2048 + (TP2) * 64 +                     \
                      ((sslot ^ (row_ & 7)) << 3),                            \
                  dst_ + i_ * 16384 + tid * 16);                              \
    }                                                                         \
  } while (0)

#define LDA4(DST, KS)                                                         \
  _Pragma("unroll") for (int mi_ = 0; mi_ < 4; ++mi_)                         \
      (DST)[mi_] = *(const short8*)(Ab +                                      \
          ((wm + mi_ * 16 + l15) << 7) + (s0 ^ ((KS) << 6)));

#define LDB4(DST, KS)                                                         \
  _Pragma("unroll") for (int ni_ = 0; ni_ < 4; ++ni_)                         \
      (DST)[ni_] = *(const short8*)(Bb +                                      \
          ((wn + ni_ * 16 + l15) << 7) + (s0 ^ ((KS) << 6)));

#define MFMA16(AR, BR)                                                        \
  do {                                                                        \
    _Pragma("unroll") for (int mi_ = 0; mi_ < 4; ++mi_)                       \
      _Pragma("unroll") for (int ni_ = 0; ni_ < 4; ++ni_)                     \
        asm("v_mfma_f32_16x16x32_bf16 %0, %1, %2, %0"                         \
            : "+v"(acc[mi_][ni_])                                             \
            : "v"((AR)[mi_]), "v"((BR)[ni_]));                                \
  } while (0)

  // prologue: A(0)->buf0, B(0)->buf0, B(1)->buf1; gate leaves B(1) in flight
  GLD_A(0);
  GLD_B(0, 0);
  GLD_B(1, 1);
  asm volatile("s_waitcnt vmcnt(2)" ::: "memory");
  __builtin_amdgcn_s_barrier();

  int bc = 0;                                  // B buffer index for tile t
  for (int t = 0; t < 32; ++t) {
    const char* Ab = smem + ((t & 1) << 15);
    const char* Bb = smem + 65536 + bc * 32768;
    const int bn2 = (bc == 0) ? 2 : bc - 1;    // (bc+2)%3
    short8 a0[4], b0[4], a1[4], b1[4];

    // ----- tile top: issue both prefetches immediately -----
    if (t < 31) GLD_A(t + 1);
    if (t < 30) GLD_B(t + 2, bn2);     // buf last read at t-1 -> WAR safe
    LDB4(b0, 0);
    LDA4(a0, 0);
    MFMA16(a0, b0);                    // c0 — compiler-counted lgkm waits
    LDB4(b1, 1);
    LDA4(a1, 1);
    MFMA16(a1, b1);                    // c1
    if (t == 30)     asm volatile("s_waitcnt vmcnt(0)" ::: "memory");
    else if (t < 30) asm volatile("s_waitcnt vmcnt(2)" ::: "memory");
    if (t < 31) __builtin_amdgcn_s_barrier();
    bc = (bc == 2) ? 0 : bc + 1;
  }

#undef GLD_A
#undef GLD_B
#undef LDA4
#undef LDB4
#undef MFMA16

  // epilogue: fused RoPE. C layout: col=lane&15, row=(lane>>4)*4+reg.
#pragma unroll
  for (int ni = 0; ni < 4; ++ni) {
    const int col = n0 + wn + ni * 16 + l15;
    const int sec = col >> 11;                 // 0=q,1=k,2=v
    const int lc  = col & 2047;
    float c = 1.0f, ssg = 0.0f;
    if (sec < 2) {
      const int h = lc >> 7;
      const int p = (lc & 127) >> 1;
      const float theta = exp2f(-(float)p * 0.20762050593046014f); // log2(1e4)/64
      float s;
      sincosf((float)h * theta, &s, &c);
      ssg = (l15 & 1) ? s : -s;
    }
    float* outp = Out + (size_t)sec * 33554432 + lc;
#pragma unroll
    for (int mi = 0; mi < 4; ++mi) {
      const f32x4 a = acc[mi][ni];
#pragma unroll
      for (int r = 0; r < 4; ++r) {
        const float val = a[r];
        float res = val;
        if (sec < 2) {
          const float other = __shfl_xor(val, 1);
          res = val * c + other * ssg;
        }
        __builtin_nontemporal_store(
            res, outp + (size_t)(m0 + wm + mi * 16 + lg * 4 + r) * 2048);
      }
    }
  }
}

extern "C" void kernel_launch(void* const* d_in, const int* in_sizes, int n_in,
                              void* d_out, int out_size, void* d_ws, size_t ws_size,
                              hipStream_t stream) {
  (void)in_sizes; (void)n_in; (void)out_size; (void)ws_size;
  const float* x  = (const float*)d_in[0];
  const float* Wq = (const float*)d_in[1];
  const float* Wk = (const float*)d_in[2];
  const float* Wv = (const float*)d_in[3];
  float* out = (float*)d_out;

  const size_t XB_ELEMS = 16384ull * 2048;

  unsigned short* Xb  = (unsigned short*)d_ws;
  unsigned short* WTf = Xb + XB_ELEMS;

  // merged prep: z=0..2 transpose Wq/Wk/Wv (32x32 blocks), z=3 convert x
  prep_all<<<dim3(32, 32, 4), 256, 0, stream>>>(x, Wq, Wk, Wv, Xb, WTf);

  hipFuncSetAttribute((const void*)qkv_fused21,
                      hipFuncAttributeMaxDynamicSharedMemorySize, 163840);
  qkv_fused21<<<1536, 1024, 163840, stream>>>(Xb, WTf, out);
}